// Round 1
// baseline (534.545 us; speedup 1.0000x reference)
//
#include <hip/hip_runtime.h>
#include <cstddef>
#include <cstdint>

#define T_STEPS 98
#define CAP1 152   // max |active L1| per step (bound: 25*5 + 22 = 147)
#define CAP2 80    // max |active L2| per step (bound: 13*5 + 13 = 78)
#define CAP3 48    // max |active L3| per step (bound: 7*5 + 7 = 42)

// workspace offsets in 4-byte units
#define OFF_CNT1 0
#define OFF_CNT2 98
#define OFF_CNT3 196
#define OFF_ACT1 512
#define OFF_ACT2 (OFF_ACT1 + T_STEPS*CAP1)
#define OFF_ACT3 (OFF_ACT2 + T_STEPS*CAP2)
#define OFF_B1P  (OFF_ACT3 + T_STEPS*CAP3)
#define OFF_B2P  (OFF_B1P + T_STEPS*CAP1)
#define OFF_B3P  (OFF_B2P + T_STEPS*CAP2)
#define OFF_W1P  55424                          // 32B-aligned region start
#define OFF_W2P  (OFF_W1P + T_STEPS*CAP1*8)
#define OFF_W3P  (OFF_W2P + T_STEPS*CAP1*CAP2)
#define OFF_W4P  (OFF_W3P + T_STEPS*CAP2*CAP3)
// total = OFF_W4P + 98*48*12 = 1,799,040 floats = ~7.2 MB of d_ws

// ---------------------------------------------------------------------------
// Setup: per timestep t, build sorted active-neuron lists from the masks and
// gather packed weight slices so the main loop reads coalesced, contiguous rows.
// ---------------------------------------------------------------------------
__global__ __launch_bounds__(512) void k_setup(
    const float* __restrict__ w1, const float* __restrict__ b1,
    const float* __restrict__ w2, const float* __restrict__ b2,
    const float* __restrict__ w3, const float* __restrict__ b3,
    const float* __restrict__ w4,
    const int* __restrict__ m1, const int* __restrict__ m2, const int* __restrict__ m3,
    float* __restrict__ wsF)
{
  int* wsI = (int*)wsF;
  const int t = blockIdx.x;
  const int tid = threadIdx.x;
  const int lane = tid & 63, wv = tid >> 6;
  __shared__ int wtot[8], wbase[8];
  __shared__ int sa1[CAP1], sa2[CAP2], sa3[CAP3];
  __shared__ int scnt[3];
  const int* ms[3] = {m1, m2, m3};
  int* sas[3] = {sa1, sa2, sa3};
  const int caps[3] = {CAP1, CAP2, CAP3};

  for (int L = 0; L < 3; ++L) {
    bool p = (ms[L][tid*T_STEPS + t] != 0);   // mask[neuron=tid][t]
    unsigned long long mk = __ballot(p);
    if (lane == 0) wtot[wv] = __popcll(mk);
    __syncthreads();
    if (tid == 0) {
      int s = 0;
      for (int q = 0; q < 8; ++q) { wbase[q] = s; s += wtot[q]; }
      scnt[L] = (s > caps[L]) ? caps[L] : s;
    }
    __syncthreads();
    int pos = wbase[wv] + __popcll(mk & ((1ull << lane) - 1ull));
    if (p && pos < caps[L]) sas[L][pos] = tid;   // sorted ascending neuron id
    __syncthreads();
  }
  const int c1 = scnt[0], c2 = scnt[1], c3 = scnt[2];

  if (tid == 0) { wsI[OFF_CNT1 + t] = c1; wsI[OFF_CNT2 + t] = c2; wsI[OFF_CNT3 + t] = c3; }
  for (int i = tid; i < c1; i += 512) wsI[OFF_ACT1 + t*CAP1 + i] = sa1[i];
  for (int i = tid; i < c2; i += 512) wsI[OFF_ACT2 + t*CAP2 + i] = sa2[i];
  for (int i = tid; i < c3; i += 512) wsI[OFF_ACT3 + t*CAP3 + i] = sa3[i];

  // packed weights / biases
  for (int i = tid; i < c1; i += 512) {
    int k = sa1[i];
    #pragma unroll
    for (int j = 0; j < 8; ++j)
      wsF[OFF_W1P + ((size_t)t*CAP1 + i)*8 + j] = w1[k*8 + j];
    wsF[OFF_B1P + t*CAP1 + i] = b1[k];
  }
  for (int l = tid; l < c2; l += 512) wsF[OFF_B2P + t*CAP2 + l] = b2[sa2[l]];
  for (int l = tid; l < c3; l += 512) wsF[OFF_B3P + t*CAP3 + l] = b3[sa3[l]];

  for (int q = tid; q < c1*CAP2; q += 512) {       // W2p[t][i][l] = w2[act2[l]][act1[i]]
    int i = q / CAP2, l = q - i*CAP2;
    if (l < c2) wsF[OFF_W2P + ((size_t)t*CAP1 + i)*CAP2 + l] = w2[(size_t)sa2[l]*512 + sa1[i]];
  }
  for (int q = tid; q < c2*CAP3; q += 512) {       // W3p[t][i][l] = w3[act3[l]][act2[i]]
    int i = q / CAP3, l = q - i*CAP3;
    if (l < c3) wsF[OFF_W3P + ((size_t)t*CAP2 + i)*CAP3 + l] = w3[(size_t)sa3[l]*512 + sa2[i]];
  }
  for (int q = tid; q < c3*12; q += 512) {         // W4p[t][i][o] = w4[o][act3[i]]
    int i = q / 12, o = q - i*12;
    if (o < 10) wsF[OFF_W4P + ((size_t)t*CAP3 + i)*12 + o] = w4[(size_t)o*512 + sa3[i]];
  }
}

// ---------------------------------------------------------------------------
// Main: one wave per batch element, persistent over all 98 timesteps.
// State (mem, last-spike-step) lives in per-wave LDS; no grid sync anywhere.
// Spikes are binary -> layer "matmul" = sum of packed weight rows for fired
// inputs (compacted per step via ballot).
// ---------------------------------------------------------------------------
__global__ __launch_bounds__(256) void k_main(
    const float* __restrict__ x, const float* __restrict__ b4,
    const float* __restrict__ wsF, float* __restrict__ out)
{
  const int* wsI = (const int*)wsF;
  const int lane = threadIdx.x & 63;
  const int w = threadIdx.x >> 6;
  const int elem = blockIdx.x * 4 + w;

  __shared__ float s_mem[4][1536];          // [wave][layer*512 + neuron]
  __shared__ signed char s_last[4][1536];   // last step the neuron fired
  __shared__ unsigned char s_f1[4][CAP1];   // fired positions within active list
  __shared__ unsigned char s_f2[4][CAP2];
  __shared__ unsigned char s_f3[4][CAP3];

  for (int i = lane; i < 1536; i += 64) { s_mem[w][i] = 0.f; s_last[w][i] = (signed char)-100; }

  float osum = 0.f;
  const float* xrow = x + (size_t)elem * 784;

  for (int t = 0; t < T_STEPS; ++t) {
    __syncthreads();   // keeps the 4 waves loosely aligned for L1-cache slice reuse
    const int c1 = wsI[OFF_CNT1 + t], c2 = wsI[OFF_CNT2 + t], c3 = wsI[OFF_CNT3 + t];
    const int st = (8*t < 90) ? 8*t : 776;   // faithful to reference slicing
    float xv[8];
    #pragma unroll
    for (int j = 0; j < 8; ++j) xv[j] = xrow[st + j];
    const signed char tm1 = (signed char)(t - 1);

    // ---- Layer 1 ----
    int nf1 = 0;
    for (int c0 = 0; c0 < c1; c0 += 64) {
      const int i = c0 + lane;
      bool p = false;
      if (i < c1) {
        const int k = wsI[OFF_ACT1 + t*CAP1 + i];
        const float4* wr = reinterpret_cast<const float4*>(wsF + OFF_W1P + ((size_t)t*CAP1 + i)*8);
        const float4 A = wr[0], B = wr[1];
        const float dot = A.x*xv[0] + A.y*xv[1] + A.z*xv[2] + A.w*xv[3]
                        + B.x*xv[4] + B.y*xv[5] + B.z*xv[6] + B.w*xv[7];
        const float memv = s_mem[w][k];
        const float spv = (s_last[w][k] == tm1) ? 1.f : 0.f;
        const float nv = memv * 0.5f * (1.f - spv) + dot + wsF[OFF_B1P + t*CAP1 + i];
        s_mem[w][k] = nv;
        p = nv > 0.3f;
        if (p) s_last[w][k] = (signed char)t;
      }
      const unsigned long long mk = __ballot(p);
      if (p) s_f1[w][nf1 + __popcll(mk & ((1ull << lane) - 1ull))] = (unsigned char)i;
      nf1 += __popcll(mk);
    }

    // ---- Layer 2 ----  (c2 in [65,78]: lane covers l=lane, and l=lane+64 when valid)
    int nf2 = 0;
    {
      const float* wb = wsF + OFF_W2P + (size_t)t*CAP1*CAP2 + lane;
      float lo0=0.f, lo1=0.f, hi0=0.f, hi1=0.f;
      int f = 0;
      for (; f + 8 <= nf1; f += 8) {
        const int i0=s_f1[w][f+0], i1=s_f1[w][f+1], i2=s_f1[w][f+2], i3=s_f1[w][f+3];
        const int i4=s_f1[w][f+4], i5=s_f1[w][f+5], i6=s_f1[w][f+6], i7=s_f1[w][f+7];
        const float* q0=wb+(size_t)i0*CAP2; const float* q1=wb+(size_t)i1*CAP2;
        const float* q2=wb+(size_t)i2*CAP2; const float* q3=wb+(size_t)i3*CAP2;
        const float* q4=wb+(size_t)i4*CAP2; const float* q5=wb+(size_t)i5*CAP2;
        const float* q6=wb+(size_t)i6*CAP2; const float* q7=wb+(size_t)i7*CAP2;
        const float a0=q0[0],a1=q1[0],a2=q2[0],a3=q3[0],a4=q4[0],a5=q5[0],a6=q6[0],a7=q7[0];
        const float h0=q0[64],h1=q1[64],h2=q2[64],h3=q3[64],h4=q4[64],h5=q5[64],h6=q6[64],h7=q7[64];
        lo0 += a0; lo1 += a1; lo0 += a2; lo1 += a3; lo0 += a4; lo1 += a5; lo0 += a6; lo1 += a7;
        hi0 += h0; hi1 += h1; hi0 += h2; hi1 += h3; hi0 += h4; hi1 += h5; hi0 += h6; hi1 += h7;
      }
      for (; f < nf1; ++f) {
        const float* q = wb + (size_t)s_f1[w][f]*CAP2;
        lo0 += q[0]; hi0 += q[64];
      }
      const float accLo = lo0 + lo1, accHi = hi0 + hi1;
      {
        bool p = false;
        if (lane < c2) {
          const int k2 = wsI[OFF_ACT2 + t*CAP2 + lane];
          const float memv = s_mem[w][512 + k2];
          const float spv = (s_last[w][512 + k2] == tm1) ? 1.f : 0.f;
          const float nv = memv * 0.5f * (1.f - spv) + accLo + wsF[OFF_B2P + t*CAP2 + lane];
          s_mem[w][512 + k2] = nv;
          p = nv > 0.3f;
          if (p) s_last[w][512 + k2] = (signed char)t;
        }
        const unsigned long long mk = __ballot(p);
        if (p) s_f2[w][__popcll(mk & ((1ull << lane) - 1ull))] = (unsigned char)lane;
        nf2 = __popcll(mk);
      }
      {
        const int l = lane + 64;
        bool p = false;
        if (l < c2) {
          const int k2 = wsI[OFF_ACT2 + t*CAP2 + l];
          const float memv = s_mem[w][512 + k2];
          const float spv = (s_last[w][512 + k2] == tm1) ? 1.f : 0.f;
          const float nv = memv * 0.5f * (1.f - spv) + accHi + wsF[OFF_B2P + t*CAP2 + l];
          s_mem[w][512 + k2] = nv;
          p = nv > 0.3f;
          if (p) s_last[w][512 + k2] = (signed char)t;
        }
        const unsigned long long mk = __ballot(p);
        if (p) s_f2[w][nf2 + __popcll(mk & ((1ull << lane) - 1ull))] = (unsigned char)l;
        nf2 += __popcll(mk);
      }
    }

    // ---- Layer 3 ----  (c3 <= 42 < 64: single chunk)
    int nf3 = 0;
    {
      const float* wb3 = wsF + OFF_W3P + (size_t)t*CAP2*CAP3 + lane;
      bool p = false;
      if (lane < c3) {
        float a0=0.f, a1=0.f, a2=0.f, a3=0.f;
        int f = 0;
        for (; f + 4 <= nf2; f += 4) {
          const int i0=s_f2[w][f+0], i1=s_f2[w][f+1], i2=s_f2[w][f+2], i3=s_f2[w][f+3];
          a0 += wb3[(size_t)i0*CAP3]; a1 += wb3[(size_t)i1*CAP3];
          a2 += wb3[(size_t)i2*CAP3]; a3 += wb3[(size_t)i3*CAP3];
        }
        for (; f < nf2; ++f) a0 += wb3[(size_t)s_f2[w][f]*CAP3];
        const float acc = (a0 + a1) + (a2 + a3);
        const int k3 = wsI[OFF_ACT3 + t*CAP3 + lane];
        const float memv = s_mem[w][1024 + k3];
        const float spv = (s_last[w][1024 + k3] == tm1) ? 1.f : 0.f;
        const float nv = memv * 0.5f * (1.f - spv) + acc + wsF[OFF_B3P + t*CAP3 + lane];
        s_mem[w][1024 + k3] = nv;
        p = nv > 0.3f;
        if (p) s_last[w][1024 + k3] = (signed char)t;
      }
      const unsigned long long mk = __ballot(p);
      if (p) s_f3[w][__popcll(mk & ((1ull << lane) - 1ull))] = (unsigned char)lane;
      nf3 = __popcll(mk);
    }

    // ---- Output accumulation ----
    if (lane < 10) {
      float o = 0.f;
      for (int f = 0; f < nf3; ++f)
        o += wsF[OFF_W4P + ((size_t)t*CAP3 + s_f3[w][f])*12 + lane];
      osum += o;
    }
  }

  if (lane < 10) out[(size_t)elem*10 + lane] = osum / 98.f + b4[lane];
}

extern "C" void kernel_launch(void* const* d_in, const int* in_sizes, int n_in,
                              void* d_out, int out_size, void* d_ws, size_t ws_size,
                              hipStream_t stream)
{
  const float* x  = (const float*)d_in[0];
  const float* w1 = (const float*)d_in[1];
  const float* b1 = (const float*)d_in[2];
  const float* w2 = (const float*)d_in[3];
  const float* b2 = (const float*)d_in[4];
  const float* w3 = (const float*)d_in[5];
  const float* b3 = (const float*)d_in[6];
  const float* w4 = (const float*)d_in[7];
  const float* b4 = (const float*)d_in[8];
  const int* m1 = (const int*)d_in[9];
  const int* m2 = (const int*)d_in[10];
  const int* m3 = (const int*)d_in[11];
  float* wsF = (float*)d_ws;
  float* out = (float*)d_out;

  hipLaunchKernelGGL(k_setup, dim3(T_STEPS), dim3(512), 0, stream,
                     w1, b1, w2, b2, w3, b3, w4, m1, m2, m3, wsF);
  hipLaunchKernelGGL(k_main, dim3(128), dim3(256), 0, stream, x, b4, wsF, out);
}

// Round 2
// 375.004 us; speedup vs baseline: 1.4254x; 1.4254x over previous
//
#include <hip/hip_runtime.h>
#include <cstddef>
#include <cstdint>

#define T_STEPS 98
#define CAP1 136   // exact bound per step: 131
#define CAP2 72    // exact bound: 68
#define CAP3 40    // exact bound: 37

// per-step blob layout (float offsets)
#define BLOBF   14848          // 59,392 bytes = 58 * 1024 exactly
#define OB_CNT  0              // 3 ints + pad
#define OB_ACT1 4              // 136 ints
#define OB_ACT2 140            // 72 ints
#define OB_ACT3 212            // 40 ints
#define OB_B1   252            // 136 f
#define OB_B2   388            // 72 f
#define OB_B3   460            // 40 f
#define OB_W4   500            // 40*12 = 480 f   [f3][out]
#define OB_W1T  980            // 8*136 = 1088 f  [j][i]  (transposed)
#define OB_W3   2068           // 72*40 = 2880 f  [i][l]
#define OB_W2   4948           // 136*72 = 9792 f [i][l]
// used end: 14740, padded to 14848

__device__ __forceinline__ void gld16(const float* g, float* l) {
  __builtin_amdgcn_global_load_lds(
      (const __attribute__((address_space(1))) float*)g,
      (__attribute__((address_space(3))) float*)l, 16, 0, 0);
}

// ---------------------------------------------------------------------------
// Setup: build per-step contiguous blobs (active lists + packed weights).
// ---------------------------------------------------------------------------
__global__ __launch_bounds__(512) void k_setup(
    const float* __restrict__ w1, const float* __restrict__ b1,
    const float* __restrict__ w2, const float* __restrict__ b2,
    const float* __restrict__ w3, const float* __restrict__ b3,
    const float* __restrict__ w4,
    const int* __restrict__ m1, const int* __restrict__ m2, const int* __restrict__ m3,
    float* __restrict__ wsF)
{
  const int t = blockIdx.x;
  const int tid = threadIdx.x;
  const int lane = tid & 63, wv = tid >> 6;
  __shared__ int wtot[8], wbase[8];
  __shared__ int sa1[CAP1], sa2[CAP2], sa3[CAP3];
  __shared__ int scnt[3];
  const int* ms[3] = {m1, m2, m3};
  int* sas[3] = {sa1, sa2, sa3};
  const int caps[3] = {CAP1, CAP2, CAP3};

  for (int L = 0; L < 3; ++L) {
    bool p = (ms[L][tid*T_STEPS + t] != 0);
    unsigned long long mk = __ballot(p);
    if (lane == 0) wtot[wv] = __popcll(mk);
    __syncthreads();
    if (tid == 0) {
      int s = 0;
      for (int q = 0; q < 8; ++q) { wbase[q] = s; s += wtot[q]; }
      scnt[L] = (s > caps[L]) ? caps[L] : s;
    }
    __syncthreads();
    int pos = wbase[wv] + __popcll(mk & ((1ull << lane) - 1ull));
    if (p && pos < caps[L]) sas[L][pos] = tid;
    __syncthreads();
  }
  const int c1 = scnt[0], c2 = scnt[1], c3 = scnt[2];

  float* blob = wsF + (size_t)t * BLOBF;
  int* blobI = (int*)blob;
  if (tid == 0) { blobI[OB_CNT] = c1; blobI[OB_CNT+1] = c2; blobI[OB_CNT+2] = c3; blobI[OB_CNT+3] = 0; }
  for (int i = tid; i < c1; i += 512) { blobI[OB_ACT1 + i] = sa1[i]; blob[OB_B1 + i] = b1[sa1[i]]; }
  for (int l = tid; l < c2; l += 512) { blobI[OB_ACT2 + l] = sa2[l]; blob[OB_B2 + l] = b2[sa2[l]]; }
  for (int l = tid; l < c3; l += 512) { blobI[OB_ACT3 + l] = sa3[l]; blob[OB_B3 + l] = b3[sa3[l]]; }

  for (int q = tid; q < c1*8; q += 512) {            // W1 transposed [j][i]
    int i = q >> 3, j = q & 7;
    blob[OB_W1T + j*CAP1 + i] = w1[sa1[i]*8 + j];
  }
  for (int q = tid; q < c1*CAP2; q += 512) {         // W2p[i][l] = w2[act2[l]][act1[i]]
    int i = q / CAP2, l = q - i*CAP2;
    if (l < c2) blob[OB_W2 + i*CAP2 + l] = w2[(size_t)sa2[l]*512 + sa1[i]];
  }
  for (int q = tid; q < c2*CAP3; q += 512) {         // W3p[i][l] = w3[act3[l]][act2[i]]
    int i = q / CAP3, l = q - i*CAP3;
    if (l < c3) blob[OB_W3 + i*CAP3 + l] = w3[(size_t)sa3[l]*512 + sa2[i]];
  }
  for (int q = tid; q < c3*12; q += 512) {           // W4p[i][o] = w4[o][act3[i]]
    int i = q / 12, o = q - i*12;
    if (o < 10) blob[OB_W4 + i*12 + o] = w4[(size_t)o*512 + sa3[i]];
  }
}

// ---------------------------------------------------------------------------
// Main: 4 elements per block (one per wave); per-step blob double-buffered in
// LDS via async global_load_lds, prefetched one full step ahead. All gathers
// are LDS reads. No spike-state needed (consecutive-step activity impossible).
// ---------------------------------------------------------------------------
__global__ __launch_bounds__(256) void k_main(
    const float* __restrict__ x, const float* __restrict__ b4,
    const float* __restrict__ wsF, float* __restrict__ out)
{
  const int lane = threadIdx.x & 63;
  const int w = threadIdx.x >> 6;
  const int elem = blockIdx.x * 4 + w;

  __shared__ float s_blob[2][BLOBF];                 // 118,784 B
  __shared__ float s_mem[4][1536];                   //  24,576 B
  __shared__ alignas(8) unsigned char s_f1[4][CAP1];
  __shared__ alignas(8) unsigned char s_f2[4][CAP2];
  __shared__ alignas(8) unsigned char s_f3[4][CAP3];

  for (int i = lane; i < 1536; i += 64) s_mem[w][i] = 0.f;

  const float* xrow = x + (size_t)elem * 784;
  float4 xA = *(const float4*)(xrow);                // slice(0) = [0,8)
  float4 xB = *(const float4*)(xrow + 4);

  // stage step 0 into buf 0
  for (int i = w; i < 58; i += 4)
    gld16(wsF + (size_t)i*256 + lane*4, &s_blob[0][i*256]);

  float osum = 0.f;
  __syncthreads();   // drains vmcnt: staging + x ready

  for (int t = 0; t < T_STEPS; ++t) {
    const float* B = s_blob[t & 1];
    const int* Bi = (const int*)B;

    // issue staging for t+1 (completes during this step's compute)
    if (t < T_STEPS - 1) {
      const float* src = wsF + (size_t)(t+1) * BLOBF;
      float* dst = (float*)s_blob[(t+1) & 1];
      for (int i = w; i < 58; i += 4)
        gld16(src + (size_t)i*256 + lane*4, dst + i*256);
    }

    const int c1 = Bi[OB_CNT], c2 = Bi[OB_CNT+1], c3 = Bi[OB_CNT+2];
    const float xv0 = xA.x, xv1 = xA.y, xv2 = xA.z, xv3 = xA.w;
    const float xv4 = xB.x, xv5 = xB.y, xv6 = xB.z, xv7 = xB.w;
    // register-prefetch next step's x slice (constant 776 for t>=12)
    if (t < 11)       { xA = *(const float4*)(xrow + 8*(t+1)); xB = *(const float4*)(xrow + 8*(t+1) + 4); }
    else if (t == 11) { xA = *(const float4*)(xrow + 776);     xB = *(const float4*)(xrow + 780); }

    // ---- Layer 1 ----
    int nf1 = 0;
    for (int c0 = 0; c0 < c1; c0 += 64) {
      const int i = c0 + lane;
      bool p = false;
      if (i < c1) {
        const int k = Bi[OB_ACT1 + i];
        const float* w1t = B + OB_W1T + i;
        const float dot = w1t[0]*xv0     + w1t[136]*xv1   + w1t[272]*xv2   + w1t[408]*xv3
                        + w1t[544]*xv4   + w1t[680]*xv5   + w1t[816]*xv6   + w1t[952]*xv7;
        const float nv = s_mem[w][k]*0.5f + dot + B[OB_B1 + i];
        s_mem[w][k] = nv;
        p = nv > 0.3f;
      }
      const unsigned long long mk = __ballot(p);
      if (p) s_f1[w][nf1 + __popcll(mk & ((1ull << lane) - 1ull))] = (unsigned char)i;
      nf1 += __popcll(mk);
    }

    // ---- Layer 2 ----
    int nf2 = 0;
    {
      const float* w2b = B + OB_W2 + lane;
      float a0=0.f,a1=0.f,a2=0.f,a3=0.f,a4=0.f,a5=0.f,a6=0.f,a7=0.f;
      int f = 0;
      for (; f + 8 <= nf1; f += 8) {
        const uint64_t pk = *(const uint64_t*)&s_f1[w][f];
        const int i0 = (int)(pk      ) & 255, i1 = (int)(pk >>  8) & 255;
        const int i2 = (int)(pk >> 16) & 255, i3 = (int)(pk >> 24) & 255;
        const int i4 = (int)(pk >> 32) & 255, i5 = (int)(pk >> 40) & 255;
        const int i6 = (int)(pk >> 48) & 255, i7 = (int)(pk >> 56);
        a0 += w2b[i0*CAP2]; a1 += w2b[i1*CAP2]; a2 += w2b[i2*CAP2]; a3 += w2b[i3*CAP2];
        a4 += w2b[i4*CAP2]; a5 += w2b[i5*CAP2]; a6 += w2b[i6*CAP2]; a7 += w2b[i7*CAP2];
      }
      for (; f < nf1; ++f) a0 += w2b[(int)s_f1[w][f]*CAP2];
      const float accLo = ((a0+a1)+(a2+a3)) + ((a4+a5)+(a6+a7));
      // outputs l = lane (always < c2 since c2 >= 67)
      {
        bool p = false;
        if (lane < c2) {
          const int k2 = Bi[OB_ACT2 + lane];
          const float nv = s_mem[w][512 + k2]*0.5f + accLo + B[OB_B2 + lane];
          s_mem[w][512 + k2] = nv;
          p = nv > 0.3f;
        }
        const unsigned long long mk = __ballot(p);
        if (p) s_f2[w][__popcll(mk & ((1ull << lane) - 1ull))] = (unsigned char)lane;
        nf2 = __popcll(mk);
      }
      // overflow outputs l = 64 + (lane>>4): 16-lane-strided gather + reduce
      {
        const int g = lane >> 4;
        const int l = 64 + g;
        float a = 0.f;
        for (int f2 = lane & 15; f2 < nf1; f2 += 16)
          a += B[OB_W2 + (int)s_f1[w][f2]*CAP2 + l];
        a += __shfl_xor(a, 1); a += __shfl_xor(a, 2);
        a += __shfl_xor(a, 4); a += __shfl_xor(a, 8);
        bool p = false;
        if ((lane & 15) == 0 && l < c2) {
          const int k2 = Bi[OB_ACT2 + l];
          const float nv = s_mem[w][512 + k2]*0.5f + a + B[OB_B2 + l];
          s_mem[w][512 + k2] = nv;
          p = nv > 0.3f;
        }
        const unsigned long long mk = __ballot(p);
        if (p) s_f2[w][nf2 + __popcll(mk & ((1ull << lane) - 1ull))] = (unsigned char)l;
        nf2 += __popcll(mk);
      }
    }

    // ---- Layer 3 ---- (c3 <= 40)
    int nf3 = 0;
    {
      bool p = false;
      if (lane < c3) {
        const float* w3b = B + OB_W3 + lane;
        float a0=0.f,a1=0.f,a2=0.f,a3=0.f;
        int f = 0;
        for (; f + 8 <= nf2; f += 8) {
          const uint64_t pk = *(const uint64_t*)&s_f2[w][f];
          const int i0 = (int)(pk      ) & 255, i1 = (int)(pk >>  8) & 255;
          const int i2 = (int)(pk >> 16) & 255, i3 = (int)(pk >> 24) & 255;
          const int i4 = (int)(pk >> 32) & 255, i5 = (int)(pk >> 40) & 255;
          const int i6 = (int)(pk >> 48) & 255, i7 = (int)(pk >> 56);
          a0 += w3b[i0*CAP3]; a1 += w3b[i1*CAP3]; a2 += w3b[i2*CAP3]; a3 += w3b[i3*CAP3];
          a0 += w3b[i4*CAP3]; a1 += w3b[i5*CAP3]; a2 += w3b[i6*CAP3]; a3 += w3b[i7*CAP3];
        }
        for (; f < nf2; ++f) a0 += w3b[(int)s_f2[w][f]*CAP3];
        const float acc = (a0+a1) + (a2+a3);
        const int k3 = Bi[OB_ACT3 + lane];
        const float nv = s_mem[w][1024 + k3]*0.5f + acc + B[OB_B3 + lane];
        s_mem[w][1024 + k3] = nv;
        p = nv > 0.3f;
      }
      const unsigned long long mk = __ballot(p);
      if (p) s_f3[w][__popcll(mk & ((1ull << lane) - 1ull))] = (unsigned char)lane;
      nf3 = __popcll(mk);
    }

    // ---- Output accumulation ----
    if (lane < 10) {
      float o0 = 0.f, o1 = 0.f;
      int f = 0;
      for (; f + 2 <= nf3; f += 2) {
        o0 += B[OB_W4 + (int)s_f3[w][f]  *12 + lane];
        o1 += B[OB_W4 + (int)s_f3[w][f+1]*12 + lane];
      }
      if (f < nf3) o0 += B[OB_W4 + (int)s_f3[w][f]*12 + lane];
      osum += o0 + o1;
    }

    __syncthreads();   // staging for t+1 done; everyone finished reading buf t
  }

  if (lane < 10) out[(size_t)elem*10 + lane] = osum / 98.f + b4[lane];
}

extern "C" void kernel_launch(void* const* d_in, const int* in_sizes, int n_in,
                              void* d_out, int out_size, void* d_ws, size_t ws_size,
                              hipStream_t stream)
{
  const float* x  = (const float*)d_in[0];
  const float* w1 = (const float*)d_in[1];
  const float* b1 = (const float*)d_in[2];
  const float* w2 = (const float*)d_in[3];
  const float* b2 = (const float*)d_in[4];
  const float* w3 = (const float*)d_in[5];
  const float* b3 = (const float*)d_in[6];
  const float* w4 = (const float*)d_in[7];
  const float* b4 = (const float*)d_in[8];
  const int* m1 = (const int*)d_in[9];
  const int* m2 = (const int*)d_in[10];
  const int* m3 = (const int*)d_in[11];
  float* wsF = (float*)d_ws;
  float* out = (float*)d_out;

  hipLaunchKernelGGL(k_setup, dim3(T_STEPS), dim3(512), 0, stream,
                     w1, b1, w2, b2, w3, b3, w4, m1, m2, m3, wsF);
  hipLaunchKernelGGL(k_main, dim3(128), dim3(256), 0, stream, x, b4, wsF, out);
}